// Round 5
// baseline (228.532 us; speedup 1.0000x reference)
//
#include <hip/hip_runtime.h>
#include <math.h>

#define B 2
#define S 1024
#define DIM 512
#define H 8
#define HD 64
#define EPS 1e-5f

typedef __attribute__((ext_vector_type(8))) short bf16x8;
typedef __attribute__((ext_vector_type(4))) float f32x4;
typedef unsigned short u16;
typedef unsigned int u32;

__device__ inline u16 f2bf(float f) {
    unsigned int u = __float_as_uint(f);
    return (u16)((u + 0x7FFF + ((u >> 16) & 1)) >> 16);
}
__device__ inline float bf2f(u16 v) {
    return __uint_as_float(((unsigned int)v) << 16);
}
__device__ inline void split2(float x, u16* hi, u16* lo) {
    u16 h = f2bf(x);
    *hi = h;
    *lo = f2bf(x - bf2f(h));
}
#define MFMA16(a, b, c) __builtin_amdgcn_mfma_f32_16x16x32_bf16((a), (b), (c), 0, 0, 0)

// async global->LDS, 16B per lane; lds base must be wave-uniform (HW adds lane*16)
__device__ inline void gl16(const void* g, void* l) {
    __builtin_amdgcn_global_load_lds((const __attribute__((address_space(1))) u32*)g,
                                     (__attribute__((address_space(3))) u32*)l, 16, 0, 0);
}

// ================= fused prep: x->hi/lo, W^T->hi/lo, Toeplitz tiles =================
__global__ void prep_k(const float* __restrict__ x,
                       const float* __restrict__ wq, const float* __restrict__ wk,
                       const float* __restrict__ wv, const float* __restrict__ wo,
                       const float* __restrict__ filt,
                       u16* __restrict__ xh, u16* __restrict__ xl,
                       u16* __restrict__ wqkvh, u16* __restrict__ wqkvl,
                       u16* __restrict__ woh, u16* __restrict__ wol,
                       u16* __restrict__ Th, u16* __restrict__ Tl) {
    int bid = blockIdx.x, tid = threadIdx.x;
    __shared__ float T[64][65];
    if (bid < 1024) {
        // xconv: one float4 per thread
        int i = bid * 256 + tid;
        float4 v = ((const float4*)x)[i];
        ushort4 h, l;
        split2(v.x, &h.x, &l.x); split2(v.y, &h.y, &l.y);
        split2(v.z, &h.z, &l.z); split2(v.w, &h.w, &l.w);
        ((ushort4*)xh)[i] = h; ((ushort4*)xl)[i] = l;
    } else if (bid < 1280) {
        int q = bid - 1024;
        int z = q >> 6, rem = q & 63;
        int k0 = (rem >> 3) * 64, n0 = (rem & 7) * 64;
        const float* src = (z == 0) ? wq : (z == 1) ? wk : (z == 2) ? wv : wo;
        u16* dh = (z < 3) ? (wqkvh + (size_t)z * 512 * 512) : woh;
        u16* dl = (z < 3) ? (wqkvl + (size_t)z * 512 * 512) : wol;
        #pragma unroll
        for (int p = 0; p < 16; ++p) {
            int i = tid + 256 * p; int r = i >> 6, c = i & 63;
            T[r][c] = src[(k0 + r) * 512 + n0 + c];
        }
        __syncthreads();
        #pragma unroll
        for (int p = 0; p < 16; ++p) {
            int i = tid + 256 * p; int r = i >> 6, c = i & 63;
            size_t di = (size_t)(n0 + r) * 512 + k0 + c;
            split2(T[c][r], &dh[di], &dl[di]);
        }
    } else {
        int q = bid - 1280;
        int h = q >> 4, delta = q & 15;
        size_t base = ((size_t)h * 16 + delta) << 12;
        #pragma unroll
        for (int p = 0; p < 16; ++p) {
            int i = tid + 256 * p;
            int t = i >> 6, s = i & 63;
            int idx = delta * 64 + t - s;
            float v = (idx >= 0 && idx < S) ? filt[idx * H + h] : 0.f;
            split2(v, &Th[base + i], &Tl[base + i]);
        }
    }
}

// ================= unified split-GEMM (virtual K = 3*512) =================
// C = Ah@Bh^T + Ah@Bl^T + Al@Bh^T ; A [M][512], B^T stored [N][512]
// 128x128 tile, 256 threads (2x2 waves of 64x64), gload_lds + XOR swizzle
// MODE 0: outf[m*N+n] = acc + b0[n]
// MODE 1: qkv scatter (N=1536)
template<int MODE>
__global__ __launch_bounds__(256) void gemm3k(
    const u16* __restrict__ Ah, const u16* __restrict__ Al,
    const u16* __restrict__ Bh, const u16* __restrict__ Bl,
    int N,
    const float* __restrict__ b0, const float* __restrict__ b1, const float* __restrict__ b2,
    float* __restrict__ outf,
    u16* __restrict__ qh, u16* __restrict__ ql,
    u16* __restrict__ kth, u16* __restrict__ ktl,
    u16* __restrict__ vth, u16* __restrict__ vtl)
{
    __shared__ __align__(16) u16 As[128 * 64];
    __shared__ __align__(16) u16 Bs[128 * 64];
    int tid = threadIdx.x, wv = tid >> 6, l = tid & 63;
    int wr = wv >> 1, wc = wv & 1;
    int m0 = blockIdx.x * 128, n0 = blockIdx.y * 128;
    f32x4 acc[4][4] = {};
    for (int kv = 0; kv < 24; ++kv) {
        int seg = kv >> 3, k0 = (kv & 7) * 64;
        const u16* Ab = (seg < 2) ? Ah : Al;
        const u16* Bb = (seg == 1) ? Bl : Bh;
        __syncthreads();
        #pragma unroll
        for (int j = 0; j < 4; ++j) {
            int row = (j * 4 + wv) * 8 + (l >> 3);
            int csw = (l & 7) ^ (row & 7);          // swizzled source col16
            int lo = (j * 4 + wv) * 512;            // u16 units (1KB groups)
            gl16(Ab + (size_t)(m0 + row) * 512 + k0 + csw * 8, As + lo);
            gl16(Bb + (size_t)(n0 + row) * 512 + k0 + csw * 8, Bs + lo);
        }
        __syncthreads();
        #pragma unroll
        for (int kc = 0; kc < 2; ++kc) {
            bf16x8 a[4];
            #pragma unroll
            for (int mi = 0; mi < 4; ++mi) {
                int row = wr * 64 + mi * 16 + (l & 15);
                int cb = (kc * 64 + (l >> 4) * 16) ^ ((row & 7) << 4);
                a[mi] = *(const bf16x8*)((const char*)(As + row * 64) + cb);
            }
            #pragma unroll
            for (int ni = 0; ni < 4; ++ni) {
                int rb = wc * 64 + ni * 16 + (l & 15);
                int cbb = (kc * 64 + (l >> 4) * 16) ^ ((rb & 7) << 4);
                bf16x8 b = *(const bf16x8*)((const char*)(Bs + rb * 64) + cbb);
                #pragma unroll
                for (int mi = 0; mi < 4; ++mi)
                    acc[mi][ni] = MFMA16(a[mi], b, acc[mi][ni]);
            }
        }
    }
    #pragma unroll
    for (int mi = 0; mi < 4; ++mi) {
        #pragma unroll
        for (int ni = 0; ni < 4; ++ni) {
            #pragma unroll
            for (int r = 0; r < 4; ++r) {
                int m = m0 + wr * 64 + mi * 16 + 4 * (l >> 4) + r;
                int n = n0 + wc * 64 + ni * 16 + (l & 15);
                float val = acc[mi][ni][r];
                if (MODE == 0) {
                    outf[(size_t)m * N + n] = val + b0[n];
                } else {
                    int bb = m >> 10, s = m & 1023;
                    int which = n >> 9, nn = n & 511;
                    int hh = nn >> 6, d = nn & 63;
                    int bh = bb * 8 + hh;
                    if (which == 0) {
                        val += b0[nn];
                        size_t di = ((size_t)bh * 1024 + s) * 64 + d;
                        split2(val, &qh[di], &ql[di]);
                    } else if (which == 1) {
                        val = (val + b1[nn]) * 0.125f;
                        size_t di = ((size_t)bh * 64 + d) * 1024 + s;
                        split2(val, &kth[di], &ktl[di]);
                    } else {
                        val += b2[nn];
                        size_t di = ((size_t)bh * 64 + d) * 1024 + s;
                        split2(val, &vth[di], &vtl[di]);
                    }
                }
            }
        }
    }
}

// ================= split-K causal conv (flattened 40-job triangle) =================
__global__ __launch_bounds__(256) void conv_part(
    const u16* __restrict__ kth, const u16* __restrict__ ktl,
    const u16* __restrict__ vth, const u16* __restrict__ vtl,
    const u16* __restrict__ Th, const u16* __restrict__ Tl,
    float* __restrict__ Kacc, float* __restrict__ Vacc)
{
    int jid = blockIdx.x, bh = blockIdx.y, h = bh & 7;
    int tb, ch;
    if (jid < 4)       { tb = jid; ch = 0; }
    else if (jid < 12) { int q = jid - 4;  tb = 4 + (q >> 1); ch = q & 1; }
    else if (jid < 24) { int q = jid - 12; int d3 = q / 3; tb = 8 + d3; ch = q - 3 * d3; }
    else               { int q = jid - 24; tb = 12 + (q >> 2); ch = q & 3; }
    int sb0 = ch * 4, sb1 = min(sb0 + 4, tb + 1);
    int tid = threadIdx.x, wv = tid >> 6, l = tid & 63;
    __shared__ __align__(16) u16 Ash[4096], Asl[4096];
    __shared__ __align__(16) u16 Ksh[4096], Ksl[4096], Vsh[4096], Vsl[4096];
    f32x4 aK[4] = {}, aV[4] = {};
    const size_t base = (size_t)bh * 64 * 1024;
    for (int sb = sb0; sb < sb1; ++sb) {
        __syncthreads();
        size_t tba = ((size_t)h * 16 + (tb - sb)) << 12;
        #pragma unroll
        for (int j = 0; j < 2; ++j) {
            int row = (j * 4 + wv) * 8 + (l >> 3);
            int csw = (l & 7) ^ (row & 7);
            int lo = (j * 4 + wv) * 512;
            gl16(Th + tba + row * 64 + csw * 8, Ash + lo);
            gl16(Tl + tba + row * 64 + csw * 8, Asl + lo);
            size_t gb = base + (size_t)row * 1024 + sb * 64 + csw * 8;
            gl16(kth + gb, Ksh + lo);
            gl16(ktl + gb, Ksl + lo);
            gl16(vth + gb, Vsh + lo);
            gl16(vtl + gb, Vsl + lo);
        }
        __syncthreads();
        #pragma unroll
        for (int seg = 0; seg < 3; ++seg) {
            const u16* Ase = (seg < 2) ? Ash : Asl;
            const u16* Kse = (seg == 1) ? Ksl : Ksh;
            const u16* Vse = (seg == 1) ? Vsl : Vsh;
            #pragma unroll
            for (int kc = 0; kc < 2; ++kc) {
                int ar = 16 * wv + (l & 15);
                int acb = (kc * 64 + (l >> 4) * 16) ^ ((ar & 7) << 4);
                bf16x8 a = *(const bf16x8*)((const char*)(Ase + ar * 64) + acb);
                #pragma unroll
                for (int cf = 0; cf < 4; ++cf) {
                    int br = cf * 16 + (l & 15);
                    int bcb = (kc * 64 + (l >> 4) * 16) ^ ((br & 7) << 4);
                    bf16x8 bk = *(const bf16x8*)((const char*)(Kse + br * 64) + bcb);
                    bf16x8 bv = *(const bf16x8*)((const char*)(Vse + br * 64) + bcb);
                    aK[cf] = MFMA16(a, bk, aK[cf]);
                    aV[cf] = MFMA16(a, bv, aV[cf]);
                }
            }
        }
    }
    #pragma unroll
    for (int cf = 0; cf < 4; ++cf) {
        #pragma unroll
        for (int r = 0; r < 4; ++r) {
            int tl_ = 16 * wv + 4 * (l >> 4) + r;
            int d = cf * 16 + (l & 15);
            size_t oi = ((size_t)bh * 1024 + tb * 64 + tl_) * 64 + d;
            atomicAdd(&Kacc[oi], aK[cf][r]);
            atomicAdd(&Vacc[oi], aV[cf][r]);
        }
    }
}

// ================= finalize conv: split planes + gates =================
__global__ void conv_fin(const float* __restrict__ Kacc, const float* __restrict__ Vacc,
                         const float* __restrict__ gw, const float* __restrict__ gb,
                         u16* __restrict__ kcth, u16* __restrict__ kctl,
                         u16* __restrict__ vcrh, u16* __restrict__ vcrl,
                         u16* __restrict__ vcth, u16* __restrict__ vctl,
                         float* __restrict__ g) {
    int sc = blockIdx.x, bh = blockIdx.y;
    int tid = threadIdx.x, tx = tid & 63, ty = tid >> 6;
    __shared__ float Kt[64][65], Vt[64][65], G[64][65];
    for (int i = tid; i < 4096; i += 256) {
        int r = i >> 6, c = i & 63;
        G[r][c] = gw[i];
        Kt[r][c] = Kacc[(((size_t)bh * 1024) + sc * 64 + r) * 64 + c];
        Vt[r][c] = Vacc[(((size_t)bh * 1024) + sc * 64 + r) * 64 + c];
    }
    __syncthreads();
    float gbias = gb[0];
    #pragma unroll
    for (int it = 0; it < 16; ++it) {
        int sl = it * 4 + ty;
        float t = 0.f;
        #pragma unroll
        for (int e = 0; e < 64; ++e) t += G[tx][e] * Kt[sl][e];
        float p = Vt[sl][tx] * t;
        #pragma unroll
        for (int off = 32; off >= 1; off >>= 1) p += __shfl_xor(p, off);
        if (tx == 0) { float gg = fmaxf(p + gbias, 0.f); g[(size_t)bh * 1024 + sc * 64 + sl] = gg * gg + EPS; }
    }
    #pragma unroll
    for (int it = 0; it < 16; ++it) {
        int r = it * 4 + ty;
        size_t ri = ((size_t)bh * 1024 + sc * 64 + r) * 64 + tx;
        split2(Vt[r][tx], &vcrh[ri], &vcrl[ri]);
    }
    #pragma unroll
    for (int it = 0; it < 16; ++it) {
        int d = it * 4 + ty;
        size_t ti = ((size_t)bh * 64 + d) * 1024 + sc * 64 + tx;
        split2(Kt[tx][d], &kcth[ti], &kctl[ti]);
        split2(Vt[tx][d], &vcth[ti], &vctl[ti]);
    }
}

// ================= inclusive scan (shfl-based, 2 barriers) =================
__global__ void scan_k(const float* __restrict__ g, float* __restrict__ cumg) {
    int bh = blockIdx.x, tid = threadIdx.x, l = tid & 63, wv = tid >> 6;
    __shared__ float wtot[4];
    float4 v = ((const float4*)(g + (size_t)bh * 1024))[tid];
    float p0 = v.x, p1 = p0 + v.y, p2 = p1 + v.z, p3 = p2 + v.w;
    float t = p3, sc = t;
    #pragma unroll
    for (int off = 1; off < 64; off <<= 1) {
        float u = __shfl_up(sc, off);
        if (l >= off) sc += u;
    }
    if (l == 63) wtot[wv] = sc;
    __syncthreads();
    float bse = sc - t;
    for (int w2 = 0; w2 < wv; ++w2) bse += wtot[w2];
    float4 o = make_float4(bse + p0, bse + p1, bse + p2, bse + p3);
    ((float4*)(cumg + (size_t)bh * 1024))[tid] = o;
}

// ================= per-block states M[e][d] = sum_s g_s khat[s][e] vhat[s][d] =================
__global__ void states_mfma(const u16* __restrict__ kcth, const u16* __restrict__ kctl,
                            const u16* __restrict__ vcth, const u16* __restrict__ vctl,
                            const float* __restrict__ g, float* __restrict__ Mst) {
    int j = blockIdx.x, bh = blockIdx.y;
    int tid = threadIdx.x, w = tid >> 6, l = tid & 63;
    __shared__ __align__(16) u16 Ash[64][72], Asl[64][72], Bsh[64][72], Bsl[64][72];
    __shared__ float gs[64];
    if (tid < 64) gs[tid] = g[(size_t)bh * 1024 + j * 64 + tid];
    __syncthreads();
    #pragma unroll
    for (int p = 0; p < 2; ++p) {
        int i = tid + 256 * p; int r = i >> 3, c8 = (i & 7) * 8;
        bf16x8 kh8 = *(const bf16x8*)&kcth[((size_t)bh * 64 + r) * 1024 + j * 64 + c8];
        bf16x8 kl8 = *(const bf16x8*)&kctl[((size_t)bh * 64 + r) * 1024 + j * 64 + c8];
        #pragma unroll
        for (int q = 0; q < 8; ++q) {
            float f = (bf2f((u16)kh8[q]) + bf2f((u16)kl8[q])) * gs[c8 + q];
            split2(f, &Ash[r][c8 + q], &Asl[r][c8 + q]);
        }
        *(bf16x8*)&Bsh[r][c8] = *(const bf16x8*)&vcth[((size_t)bh * 64 + r) * 1024 + j * 64 + c8];
        *(bf16x8*)&Bsl[r][c8] = *(const bf16x8*)&vctl[((size_t)bh * 64 + r) * 1024 + j * 64 + c8];
    }
    __syncthreads();
    f32x4 acc[4] = {};
    #pragma unroll
    for (int kc = 0; kc < 2; ++kc) {
        int ar = 16 * w + (l & 15), ac = kc * 32 + (l >> 4) * 8;
        bf16x8 ah = *(const bf16x8*)&Ash[ar][ac];
        bf16x8 al = *(const bf16x8*)&Asl[ar][ac];
        #pragma unroll
        for (int cf = 0; cf < 4; ++cf) {
            int br = cf * 16 + (l & 15);
            bf16x8 bh_ = *(const bf16x8*)&Bsh[br][ac];
            bf16x8 bl_ = *(const bf16x8*)&Bsl[br][ac];
            acc[cf] = MFMA16(ah, bh_, acc[cf]);
            acc[cf] = MFMA16(ah, bl_, acc[cf]);
            acc[cf] = MFMA16(al, bh_, acc[cf]);
        }
    }
    #pragma unroll
    for (int cf = 0; cf < 4; ++cf) {
        #pragma unroll
        for (int r = 0; r < 4; ++r) {
            int e = 16 * w + 4 * (l >> 4) + r;
            int d = cf * 16 + (l & 15);
            Mst[(((size_t)bh * 16 + j) * 64 + e) * 64 + d] = acc[cf][r];
        }
    }
}

// ================= exclusive prefix over j -> hi/lo bf16 =================
__global__ void state_prefix(const float* __restrict__ Mst,
                             u16* __restrict__ ph, u16* __restrict__ pl) {
    int bh = blockIdx.x;
    int pos = blockIdx.y * 256 + threadIdx.x;
    float run = 0.f;
    #pragma unroll
    for (int j = 0; j < 16; ++j) {
        size_t idx = ((size_t)bh * 16 + j) * 4096 + pos;
        split2(run, &ph[idx], &pl[idx]);
        run += Mst[idx];
    }
}

// ================= attention: out = Q@Pex + intra, /(cumg+eps), unit-norm =================
__global__ void attn_mfma(const u16* __restrict__ qh, const u16* __restrict__ ql,
                          const u16* __restrict__ pexh, const u16* __restrict__ pexl,
                          const u16* __restrict__ vcrh, const u16* __restrict__ vcrl,
                          const u16* __restrict__ kcth, const u16* __restrict__ kctl,
                          const float* __restrict__ g, const float* __restrict__ cumg,
                          u16* __restrict__ yh, u16* __restrict__ yl) {
    int tb = blockIdx.x, bh = blockIdx.y;
    int b = bh >> 3, h = bh & 7;
    int tid = threadIdx.x, w = tid >> 6, l = tid & 63;
    __shared__ __align__(16) u16 buf[6][64][72];
    __shared__ float gl_s[64], cg_s[64];
    #pragma unroll
    for (int p = 0; p < 2; ++p) {
        int i = tid + 256 * p; int r = i >> 3, c8 = (i & 7) * 8;
        size_t rowi = ((size_t)bh * 1024 + tb * 64 + r) * 64 + c8;
        size_t pexi = (((size_t)bh * 16 + tb) * 64 + r) * 64 + c8;
        *(bf16x8*)&buf[0][r][c8] = *(const bf16x8*)&qh[rowi];
        *(bf16x8*)&buf[1][r][c8] = *(const bf16x8*)&ql[rowi];
        *(bf16x8*)&buf[2][r][c8] = *(const bf16x8*)&pexh[pexi];
        *(bf16x8*)&buf[3][r][c8] = *(const bf16x8*)&pexl[pexi];
        *(bf16x8*)&buf[4][r][c8] = *(const bf16x8*)&vcrh[rowi];
        *(bf16x8*)&buf[5][r][c8] = *(const bf16x8*)&vcrl[rowi];
    }
    if (tid < 64) {
        gl_s[tid] = g[(size_t)bh * 1024 + tb * 64 + tid];
        cg_s[tid] = cumg[(size_t)bh * 1024 + tb * 64 + tid];
    }
    __syncthreads();
    f32x4 o[4] = {}, sc[4] = {};
    #pragma unroll
    for (int kc = 0; kc < 2; ++kc) {
        int ar = 16 * w + (l & 15), ac = kc * 32 + (l >> 4) * 8;
        bf16x8 ah = *(const bf16x8*)&buf[0][ar][ac];
        bf16x8 al = *(const bf16x8*)&buf[1][ar][ac];
        #pragma unroll
        for (int cf = 0; cf < 4; ++cf) {
            int br = cf * 16 + (l & 15);
            bf16x8 bph = *(const bf16x8*)&buf[2][br][ac];
            bf16x8 bpl = *(const bf16x8*)&buf[3][br][ac];
            bf16x8 bvh = *(const bf16x8*)&buf[4][br][ac];
            bf16x8 bvl = *(const bf16x8*)&buf[5][br][ac];
            o[cf] = MFMA16(ah, bph, o[cf]);
            o[cf] = MFMA16(ah, bpl, o[cf]);
            o[cf] = MFMA16(al, bph, o[cf]);
            sc[cf] = MFMA16(ah, bvh, sc[cf]);
            sc[cf] = MFMA16(ah, bvl, sc[cf]);
            sc[cf] = MFMA16(al, bvh, sc[cf]);
        }
    }
    __syncthreads();
    #pragma unroll
    for (int cf = 0; cf < 4; ++cf) {
        int s = cf * 16 + (l & 15);
        float gsv = gl_s[s];
        #pragma unroll
        for (int r = 0; r < 4; ++r) {
            int t = 16 * w + 4 * (l >> 4) + r;
            float v = (s <= t) ? sc[cf][r] * gsv : 0.f;
            split2(v, &buf[2][t][s], &buf[3][t][s]);
        }
    }
    #pragma unroll
    for (int p = 0; p < 2; ++p) {
        int i = tid + 256 * p; int r = i >> 3, c8 = (i & 7) * 8;
        size_t ti = ((size_t)bh * 64 + r) * 1024 + tb * 64 + c8;
        *(bf16x8*)&buf[4][r][c8] = *(const bf16x8*)&kcth[ti];
        *(bf16x8*)&buf[5][r][c8] = *(const bf16x8*)&kctl[ti];
    }
    __syncthreads();
    #pragma unroll
    for (int kc = 0; kc < 2; ++kc) {
        int ar = 16 * w + (l & 15), ac = kc * 32 + (l >> 4) * 8;
        bf16x8 ah = *(const bf16x8*)&buf[2][ar][ac];
        bf16x8 al = *(const bf16x8*)&buf[3][ar][ac];
        #pragma unroll
        for (int cf = 0; cf < 4; ++cf) {
            int br = cf * 16 + (l & 15);
            bf16x8 bh_ = *(const bf16x8*)&buf[4][br][ac];
            bf16x8 bl_ = *(const bf16x8*)&buf[5][br][ac];
            o[cf] = MFMA16(ah, bh_, o[cf]);
            o[cf] = MFMA16(ah, bl_, o[cf]);
            o[cf] = MFMA16(al, bh_, o[cf]);
        }
    }
    #pragma unroll
    for (int r = 0; r < 4; ++r) {
        int tl_ = 16 * w + 4 * (l >> 4) + r;
        float inv = 1.f / (cg_s[tl_] + EPS);
        float vv[4]; float sq = 0.f;
        #pragma unroll
        for (int cf = 0; cf < 4; ++cf) { vv[cf] = o[cf][r] * inv; sq += vv[cf] * vv[cf]; }
        #pragma unroll
        for (int off = 1; off < 16; off <<= 1) sq += __shfl_xor(sq, off);
        float scale = 1.f / fmaxf(sqrtf(sq), EPS);
        int tg = tb * 64 + tl_;
        #pragma unroll
        for (int cf = 0; cf < 4; ++cf) {
            int e = cf * 16 + (l & 15);
            size_t yi = ((size_t)b * 1024 + tg) * 512 + h * 64 + e;
            split2(vv[cf] * scale, &yh[yi], &yl[yi]);
        }
    }
}

extern "C" void kernel_launch(void* const* d_in, const int* in_sizes, int n_in,
                              void* d_out, int out_size, void* d_ws, size_t ws_size,
                              hipStream_t stream) {
    const float* x    = (const float*)d_in[0];
    const float* sbas = (const float*)d_in[1];
    const float* wq_w = (const float*)d_in[2];
    const float* wq_b = (const float*)d_in[3];
    const float* wk_w = (const float*)d_in[4];
    const float* wk_b = (const float*)d_in[5];
    const float* wv_w = (const float*)d_in[6];
    const float* wv_b = (const float*)d_in[7];
    const float* wo_w = (const float*)d_in[8];
    const float* wo_b = (const float*)d_in[9];
    const float* gw   = (const float*)d_in[10];
    const float* gb   = (const float*)d_in[11];
    float* out = (float*)d_out;

    char* p = (char*)d_ws;
    auto carve = [&](size_t bytes) { char* r = p; p += (bytes + 255) & ~(size_t)255; return r; };
    const size_t T2 = (size_t)2048 * 512 * 2;          // 2 MB (u16 plane)
    u16* xh = (u16*)carve(T2);      u16* xl = (u16*)carve(T2);
    u16* wqkvh = (u16*)carve((size_t)1536 * 512 * 2);
    u16* wqkvl = (u16*)carve((size_t)1536 * 512 * 2);
    u16* woh = (u16*)carve((size_t)512 * 512 * 2);
    u16* wol = (u16*)carve((size_t)512 * 512 * 2);
    u16* qh_ = (u16*)carve(T2);     u16* ql_ = (u16*)carve(T2);
    u16* kth_ = (u16*)carve(T2);    u16* ktl_ = (u16*)carve(T2);
    u16* vth_ = (u16*)carve(T2);    u16* vtl_ = (u16*)carve(T2);
    u16* Tth = (u16*)carve((size_t)8 * 16 * 4096 * 2);
    u16* Ttl = (u16*)carve((size_t)8 * 16 * 4096 * 2);
    float* Kacc = (float*)carve((size_t)16 * 1024 * 64 * 4);
    float* Vacc = (float*)carve((size_t)16 * 1024 * 64 * 4);
    u16* kcth_ = (u16*)carve(T2);   u16* kctl_ = (u16*)carve(T2);
    u16* vcrh_ = (u16*)carve(T2);   u16* vcrl_ = (u16*)carve(T2);
    u16* vcth_ = (u16*)carve(T2);   u16* vctl_ = (u16*)carve(T2);
    float* gbuf = (float*)carve((size_t)16 * 1024 * 4);
    float* cumg = (float*)carve((size_t)16 * 1024 * 4);
    float* Mst  = (float*)carve((size_t)16 * 16 * 4096 * 4);
    u16* pexh_ = (u16*)carve(T2);   u16* pexl_ = (u16*)carve(T2);
    u16* yh_ = (u16*)carve(T2);     u16* yl_ = (u16*)carve(T2);

    // zero both fp32 accumulators in one async memset (Kacc,Vacc contiguous)
    hipMemsetAsync(Kacc, 0, (size_t)16 * 1024 * 64 * 4 * 2, stream);
    prep_k<<<1408, 256, 0, stream>>>(x, wq_w, wk_w, wv_w, wo_w, sbas,
                                     xh, xl, wqkvh, wqkvl, woh, wol, Tth, Ttl);
    gemm3k<1><<<dim3(16, 12), 256, 0, stream>>>(xh, xl, wqkvh, wqkvl, 1536,
                                                wq_b, wk_b, wv_b, nullptr,
                                                qh_, ql_, kth_, ktl_, vth_, vtl_);
    conv_part<<<dim3(40, 16), 256, 0, stream>>>(kth_, ktl_, vth_, vtl_, Tth, Ttl, Kacc, Vacc);
    conv_fin<<<dim3(16, 16), 256, 0, stream>>>(Kacc, Vacc, gw, gb,
                                               kcth_, kctl_, vcrh_, vcrl_, vcth_, vctl_, gbuf);
    scan_k<<<16, 256, 0, stream>>>(gbuf, cumg);
    states_mfma<<<dim3(16, 16), 256, 0, stream>>>(kcth_, kctl_, vcth_, vctl_, gbuf, Mst);
    state_prefix<<<dim3(16, 16), 256, 0, stream>>>(Mst, pexh_, pexl_);
    attn_mfma<<<dim3(16, 16), 256, 0, stream>>>(qh_, ql_, pexh_, pexl_, vcrh_, vcrl_,
                                                kcth_, kctl_, gbuf, cumg, yh_, yl_);
    gemm3k<0><<<dim3(16, 4), 256, 0, stream>>>(yh_, yl_, woh, wol, 512,
                                               wo_b, nullptr, nullptr, out,
                                               nullptr, nullptr, nullptr, nullptr, nullptr, nullptr);
}

// Round 7
// 178.919 us; speedup vs baseline: 1.2773x; 1.2773x over previous
//
#include <hip/hip_runtime.h>
#include <math.h>

#define B 2
#define S 1024
#define DIM 512
#define H 8
#define HD 64
#define EPS 1e-5f

typedef __attribute__((ext_vector_type(8))) short bf16x8;
typedef __attribute__((ext_vector_type(4))) float f32x4;
typedef unsigned short u16;
typedef unsigned int u32;

__device__ inline u16 f2bf(float f) {
    unsigned int u = __float_as_uint(f);
    return (u16)((u + 0x7FFF + ((u >> 16) & 1)) >> 16);
}
__device__ inline float bf2f(u16 v) {
    return __uint_as_float(((unsigned int)v) << 16);
}
__device__ inline void split2(float x, u16* hi, u16* lo) {
    u16 h = f2bf(x);
    *hi = h;
    *lo = f2bf(x - bf2f(h));
}
#define MFMA16(a, b, c) __builtin_amdgcn_mfma_f32_16x16x32_bf16((a), (b), (c), 0, 0, 0)

// async global->LDS, 16B per lane; lds base must be wave-uniform (HW adds lane*16)
__device__ inline void gl16(const void* g, void* l) {
    __builtin_amdgcn_global_load_lds((const __attribute__((address_space(1))) u32*)g,
                                     (__attribute__((address_space(3))) u32*)l, 16, 0, 0);
}

// ================= fused prep: x->hi/lo, W^T->hi/lo, Toeplitz tiles =================
__global__ void prep_k(const float* __restrict__ x,
                       const float* __restrict__ wq, const float* __restrict__ wk,
                       const float* __restrict__ wv, const float* __restrict__ wo,
                       const float* __restrict__ filt,
                       u16* __restrict__ xh, u16* __restrict__ xl,
                       u16* __restrict__ wqkvh, u16* __restrict__ wqkvl,
                       u16* __restrict__ woh, u16* __restrict__ wol,
                       u16* __restrict__ Th, u16* __restrict__ Tl) {
    int bid = blockIdx.x, tid = threadIdx.x;
    __shared__ float T[64][65];
    if (bid < 1024) {
        int i = bid * 256 + tid;
        float4 v = ((const float4*)x)[i];
        ushort4 h, l;
        split2(v.x, &h.x, &l.x); split2(v.y, &h.y, &l.y);
        split2(v.z, &h.z, &l.z); split2(v.w, &h.w, &l.w);
        ((ushort4*)xh)[i] = h; ((ushort4*)xl)[i] = l;
    } else if (bid < 1280) {
        int q = bid - 1024;
        int z = q >> 6, rem = q & 63;
        int k0 = (rem >> 3) * 64, n0 = (rem & 7) * 64;
        const float* src = (z == 0) ? wq : (z == 1) ? wk : (z == 2) ? wv : wo;
        u16* dh = (z < 3) ? (wqkvh + (size_t)z * 512 * 512) : woh;
        u16* dl = (z < 3) ? (wqkvl + (size_t)z * 512 * 512) : wol;
        #pragma unroll
        for (int p = 0; p < 16; ++p) {
            int i = tid + 256 * p; int r = i >> 6, c = i & 63;
            T[r][c] = src[(k0 + r) * 512 + n0 + c];
        }
        __syncthreads();
        #pragma unroll
        for (int p = 0; p < 16; ++p) {
            int i = tid + 256 * p; int r = i >> 6, c = i & 63;
            size_t di = (size_t)(n0 + r) * 512 + k0 + c;
            split2(T[c][r], &dh[di], &dl[di]);
        }
    } else {
        int q = bid - 1280;
        int h = q >> 4, delta = q & 15;
        size_t base = ((size_t)h * 16 + delta) << 12;
        #pragma unroll
        for (int p = 0; p < 16; ++p) {
            int i = tid + 256 * p;
            int t = i >> 6, s = i & 63;
            int idx = delta * 64 + t - s;
            float v = (idx >= 0 && idx < S) ? filt[idx * H + h] : 0.f;
            split2(v, &Th[base + i], &Tl[base + i]);
        }
    }
}

// ================= split-GEMM: C = Ah@Bh^T + Ah@Bl^T + Al@Bh^T =================
// Tile 64 x TN; TN=128 -> 512 thr (8 waves 2x4), TN=64 -> 256 thr (4 waves 2x2).
// Stage 4 planes per real k-step (8 steps), 3 segment passes from LDS.
// MODE 0: outf[m*N+n] = acc + b0[n] ; MODE 1: qkv scatter (N=1536)
template<int TN, int MODE>
__global__ __launch_bounds__(TN * 4) void gemm3k(
    const u16* __restrict__ Ah, const u16* __restrict__ Al,
    const u16* __restrict__ Bh, const u16* __restrict__ Bl,
    int N,
    const float* __restrict__ b0, const float* __restrict__ b1, const float* __restrict__ b2,
    float* __restrict__ outf,
    u16* __restrict__ qh, u16* __restrict__ ql,
    u16* __restrict__ kth, u16* __restrict__ ktl,
    u16* __restrict__ vth, u16* __restrict__ vtl)
{
    const int NT = TN * 4;                       // threads
    __shared__ __align__(16) u16 LAh[64 * 64], LAl[64 * 64];
    __shared__ __align__(16) u16 LBh[TN * 64], LBl[TN * 64];
    int tid = threadIdx.x, l = tid & 63, wid = tid >> 6;
    int wm = wid & 1, wn = wid >> 1;             // wave tile 32x32
    int m0 = blockIdx.x * 64, n0 = blockIdx.y * TN;
    const u16* Abh = Ah + (size_t)m0 * 512;
    const u16* Abl = Al + (size_t)m0 * 512;
    const u16* Bbh = Bh + (size_t)n0 * 512;
    const u16* Bbl = Bl + (size_t)n0 * 512;
    int wbase = tid & ~63;
    f32x4 acc[2][2] = {};
    for (int k0s = 0; k0s < 8; ++k0s) {
        int k0 = k0s * 64;
        __syncthreads();
        // stage 4 planes (pre-swizzled source, linear LDS dest)
        #pragma unroll
        for (int i0 = 0; i0 < 512; i0 += NT) {
            int i = i0 + tid;
            int row = i >> 3, csw = (i & 7) ^ (row & 7);
            gl16(Abh + (size_t)row * 512 + k0 + csw * 8, LAh + (size_t)(i0 + wbase) * 8);
            gl16(Abl + (size_t)row * 512 + k0 + csw * 8, LAl + (size_t)(i0 + wbase) * 8);
        }
        #pragma unroll
        for (int i0 = 0; i0 < TN * 8; i0 += NT) {
            int i = i0 + tid;
            int row = i >> 3, csw = (i & 7) ^ (row & 7);
            gl16(Bbh + (size_t)row * 512 + k0 + csw * 8, LBh + (size_t)(i0 + wbase) * 8);
            gl16(Bbl + (size_t)row * 512 + k0 + csw * 8, LBl + (size_t)(i0 + wbase) * 8);
        }
        __syncthreads();
        #pragma unroll
        for (int kc = 0; kc < 2; ++kc) {
            bf16x8 ah[2], al[2], bh8[2], bl8[2];
            #pragma unroll
            for (int mi = 0; mi < 2; ++mi) {
                int ar = wm * 32 + mi * 16 + (l & 15);
                int ci = (kc * 4 + (l >> 4)) ^ (ar & 7);
                ah[mi] = *(const bf16x8*)(LAh + ar * 64 + ci * 8);
                al[mi] = *(const bf16x8*)(LAl + ar * 64 + ci * 8);
            }
            #pragma unroll
            for (int ni = 0; ni < 2; ++ni) {
                int br = wn * 32 + ni * 16 + (l & 15);
                int ci = (kc * 4 + (l >> 4)) ^ (br & 7);
                bh8[ni] = *(const bf16x8*)(LBh + br * 64 + ci * 8);
                bl8[ni] = *(const bf16x8*)(LBl + br * 64 + ci * 8);
            }
            #pragma unroll
            for (int mi = 0; mi < 2; ++mi)
                #pragma unroll
                for (int ni = 0; ni < 2; ++ni) {
                    acc[mi][ni] = MFMA16(ah[mi], bh8[ni], acc[mi][ni]);
                    acc[mi][ni] = MFMA16(ah[mi], bl8[ni], acc[mi][ni]);
                    acc[mi][ni] = MFMA16(al[mi], bh8[ni], acc[mi][ni]);
                }
        }
    }
    #pragma unroll
    for (int mi = 0; mi < 2; ++mi) {
        #pragma unroll
        for (int ni = 0; ni < 2; ++ni) {
            #pragma unroll
            for (int r = 0; r < 4; ++r) {
                int m = m0 + wm * 32 + mi * 16 + 4 * (l >> 4) + r;
                int n = n0 + wn * 32 + ni * 16 + (l & 15);
                float val = acc[mi][ni][r];
                if (MODE == 0) {
                    outf[(size_t)m * N + n] = val + b0[n];
                } else {
                    int bb = m >> 10, s = m & 1023;
                    int which = n >> 9, nn = n & 511;
                    int hh = nn >> 6, d = nn & 63;
                    int bh = bb * 8 + hh;
                    if (which == 0) {
                        val += b0[nn];
                        size_t di = ((size_t)bh * 1024 + s) * 64 + d;
                        split2(val, &qh[di], &ql[di]);
                    } else if (which == 1) {
                        val = (val + b1[nn]) * 0.125f;
                        size_t di = ((size_t)bh * 64 + d) * 1024 + s;
                        split2(val, &kth[di], &ktl[di]);
                    } else {
                        val += b2[nn];
                        size_t di = ((size_t)bh * 64 + d) * 1024 + s;
                        split2(val, &vth[di], &vtl[di]);
                    }
                }
            }
        }
    }
}

// ================= split-K causal conv (flattened 40-job triangle) =================
__global__ __launch_bounds__(256) void conv_part(
    const u16* __restrict__ kth, const u16* __restrict__ ktl,
    const u16* __restrict__ vth, const u16* __restrict__ vtl,
    const u16* __restrict__ Th, const u16* __restrict__ Tl,
    float* __restrict__ Kacc, float* __restrict__ Vacc)
{
    int jid = blockIdx.x, bh = blockIdx.y, h = bh & 7;
    int tb, ch;
    if (jid < 4)       { tb = jid; ch = 0; }
    else if (jid < 12) { int q = jid - 4;  tb = 4 + (q >> 1); ch = q & 1; }
    else if (jid < 24) { int q = jid - 12; int d3 = q / 3; tb = 8 + d3; ch = q - 3 * d3; }
    else               { int q = jid - 24; tb = 12 + (q >> 2); ch = q & 3; }
    int sb0 = ch * 4, sb1 = min(sb0 + 4, tb + 1);
    int tid = threadIdx.x, wv = tid >> 6, l = tid & 63;
    __shared__ __align__(16) u16 Ash[4096], Asl[4096];
    __shared__ __align__(16) u16 Ksh[4096], Ksl[4096], Vsh[4096], Vsl[4096];
    f32x4 aK[4] = {}, aV[4] = {};
    const size_t base = (size_t)bh * 64 * 1024;
    for (int sb = sb0; sb < sb1; ++sb) {
        __syncthreads();
        size_t tba = ((size_t)h * 16 + (tb - sb)) << 12;
        #pragma unroll
        for (int j = 0; j < 2; ++j) {
            int row = (j * 4 + wv) * 8 + (l >> 3);
            int csw = (l & 7) ^ (row & 7);
            int lo = (j * 4 + wv) * 512;
            gl16(Th + tba + row * 64 + csw * 8, Ash + lo);
            gl16(Tl + tba + row * 64 + csw * 8, Asl + lo);
            size_t gb = base + (size_t)row * 1024 + sb * 64 + csw * 8;
            gl16(kth + gb, Ksh + lo);
            gl16(ktl + gb, Ksl + lo);
            gl16(vth + gb, Vsh + lo);
            gl16(vtl + gb, Vsl + lo);
        }
        __syncthreads();
        #pragma unroll
        for (int seg = 0; seg < 3; ++seg) {
            const u16* Ase = (seg < 2) ? Ash : Asl;
            const u16* Kse = (seg == 1) ? Ksl : Ksh;
            const u16* Vse = (seg == 1) ? Vsl : Vsh;
            #pragma unroll
            for (int kc = 0; kc < 2; ++kc) {
                int ar = 16 * wv + (l & 15);
                int acb = (kc * 64 + (l >> 4) * 16) ^ ((ar & 7) << 4);
                bf16x8 a = *(const bf16x8*)((const char*)(Ase + ar * 64) + acb);
                #pragma unroll
                for (int cf = 0; cf < 4; ++cf) {
                    int br = cf * 16 + (l & 15);
                    int bcb = (kc * 64 + (l >> 4) * 16) ^ ((br & 7) << 4);
                    bf16x8 bk = *(const bf16x8*)((const char*)(Kse + br * 64) + bcb);
                    bf16x8 bv = *(const bf16x8*)((const char*)(Vse + br * 64) + bcb);
                    aK[cf] = MFMA16(a, bk, aK[cf]);
                    aV[cf] = MFMA16(a, bv, aV[cf]);
                }
            }
        }
    }
    #pragma unroll
    for (int cf = 0; cf < 4; ++cf) {
        #pragma unroll
        for (int r = 0; r < 4; ++r) {
            int tl_ = 16 * wv + 4 * (l >> 4) + r;
            int d = cf * 16 + (l & 15);
            size_t oi = ((size_t)bh * 1024 + tb * 64 + tl_) * 64 + d;
            atomicAdd(&Kacc[oi], aK[cf][r]);
            atomicAdd(&Vacc[oi], aV[cf][r]);
        }
    }
}

// ================= finalize conv: split planes + gates =================
__global__ void conv_fin(const float* __restrict__ Kacc, const float* __restrict__ Vacc,
                         const float* __restrict__ gw, const float* __restrict__ gb,
                         u16* __restrict__ kcth, u16* __restrict__ kctl,
                         u16* __restrict__ vcrh, u16* __restrict__ vcrl,
                         u16* __restrict__ vcth, u16* __restrict__ vctl,
                         float* __restrict__ g) {
    int sc = blockIdx.x, bh = blockIdx.y;
    int tid = threadIdx.x, tx = tid & 63, ty = tid >> 6;
    __shared__ float Kt[64][65], Vt[64][65], G[64][65];
    for (int i = tid; i < 4096; i += 256) {
        int r = i >> 6, c = i & 63;
        G[r][c] = gw[i];
        Kt[r][c] = Kacc[(((size_t)bh * 1024) + sc * 64 + r) * 64 + c];
        Vt[r][c] = Vacc[(((size_t)bh * 1024) + sc * 64 + r) * 64 + c];
    }
    __syncthreads();
    float gbias = gb[0];
    #pragma unroll
    for (int it = 0; it < 16; ++it) {
        int sl = it * 4 + ty;
        float t = 0.f;
        #pragma unroll
        for (int e = 0; e < 64; ++e) t += G[tx][e] * Kt[sl][e];
        float p = Vt[sl][tx] * t;
        #pragma unroll
        for (int off = 32; off >= 1; off >>= 1) p += __shfl_xor(p, off);
        if (tx == 0) { float gg = fmaxf(p + gbias, 0.f); g[(size_t)bh * 1024 + sc * 64 + sl] = gg * gg + EPS; }
    }
    #pragma unroll
    for (int it = 0; it < 16; ++it) {
        int r = it * 4 + ty;
        size_t ri = ((size_t)bh * 1024 + sc * 64 + r) * 64 + tx;
        split2(Vt[r][tx], &vcrh[ri], &vcrl[ri]);
    }
    #pragma unroll
    for (int it = 0; it < 16; ++it) {
        int d = it * 4 + ty;
        size_t ti = ((size_t)bh * 64 + d) * 1024 + sc * 64 + tx;
        split2(Kt[tx][d], &kcth[ti], &kctl[ti]);
        split2(Vt[tx][d], &vcth[ti], &vctl[ti]);
    }
}

// ================= inclusive scan (shfl-based, 2 barriers) =================
__global__ void scan_k(const float* __restrict__ g, float* __restrict__ cumg) {
    int bh = blockIdx.x, tid = threadIdx.x, l = tid & 63, wv = tid >> 6;
    __shared__ float wtot[4];
    float4 v = ((const float4*)(g + (size_t)bh * 1024))[tid];
    float p0 = v.x, p1 = p0 + v.y, p2 = p1 + v.z, p3 = p2 + v.w;
    float t = p3, sc = t;
    #pragma unroll
    for (int off = 1; off < 64; off <<= 1) {
        float u = __shfl_up(sc, off);
        if (l >= off) sc += u;
    }
    if (l == 63) wtot[wv] = sc;
    __syncthreads();
    float bse = sc - t;
    for (int w2 = 0; w2 < wv; ++w2) bse += wtot[w2];
    float4 o = make_float4(bse + p0, bse + p1, bse + p2, bse + p3);
    ((float4*)(cumg + (size_t)bh * 1024))[tid] = o;
}

// ================= per-block states M[e][d] = sum_s g_s khat[s][e] vhat[s][d] =================
__global__ void states_mfma(const u16* __restrict__ kcth, const u16* __restrict__ kctl,
                            const u16* __restrict__ vcth, const u16* __restrict__ vctl,
                            const float* __restrict__ g, float* __restrict__ Mst) {
    int j = blockIdx.x, bh = blockIdx.y;
    int tid = threadIdx.x, w = tid >> 6, l = tid & 63;
    __shared__ __align__(16) u16 Ash[64][72], Asl[64][72], Bsh[64][72], Bsl[64][72];
    __shared__ float gs[64];
    if (tid < 64) gs[tid] = g[(size_t)bh * 1024 + j * 64 + tid];
    __syncthreads();
    #pragma unroll
    for (int p = 0; p < 2; ++p) {
        int i = tid + 256 * p; int r = i >> 3, c8 = (i & 7) * 8;
        bf16x8 kh8 = *(const bf16x8*)&kcth[((size_t)bh * 64 + r) * 1024 + j * 64 + c8];
        bf16x8 kl8 = *(const bf16x8*)&kctl[((size_t)bh * 64 + r) * 1024 + j * 64 + c8];
        #pragma unroll
        for (int q = 0; q < 8; ++q) {
            float f = (bf2f((u16)kh8[q]) + bf2f((u16)kl8[q])) * gs[c8 + q];
            split2(f, &Ash[r][c8 + q], &Asl[r][c8 + q]);
        }
        *(bf16x8*)&Bsh[r][c8] = *(const bf16x8*)&vcth[((size_t)bh * 64 + r) * 1024 + j * 64 + c8];
        *(bf16x8*)&Bsl[r][c8] = *(const bf16x8*)&vctl[((size_t)bh * 64 + r) * 1024 + j * 64 + c8];
    }
    __syncthreads();
    f32x4 acc[4] = {};
    #pragma unroll
    for (int kc = 0; kc < 2; ++kc) {
        int ar = 16 * w + (l & 15), ac = kc * 32 + (l >> 4) * 8;
        bf16x8 ah = *(const bf16x8*)&Ash[ar][ac];
        bf16x8 al = *(const bf16x8*)&Asl[ar][ac];
        #pragma unroll
        for (int cf = 0; cf < 4; ++cf) {
            int br = cf * 16 + (l & 15);
            bf16x8 bh_ = *(const bf16x8*)&Bsh[br][ac];
            bf16x8 bl_ = *(const bf16x8*)&Bsl[br][ac];
            acc[cf] = MFMA16(ah, bh_, acc[cf]);
            acc[cf] = MFMA16(ah, bl_, acc[cf]);
            acc[cf] = MFMA16(al, bh_, acc[cf]);
        }
    }
    #pragma unroll
    for (int cf = 0; cf < 4; ++cf) {
        #pragma unroll
        for (int r = 0; r < 4; ++r) {
            int e = 16 * w + 4 * (l >> 4) + r;
            int d = cf * 16 + (l & 15);
            Mst[(((size_t)bh * 16 + j) * 64 + e) * 64 + d] = acc[cf][r];
        }
    }
}

// ================= exclusive prefix over j -> hi/lo bf16 =================
__global__ void state_prefix(const float* __restrict__ Mst,
                             u16* __restrict__ ph, u16* __restrict__ pl) {
    int bh = blockIdx.x;
    int pos = blockIdx.y * 256 + threadIdx.x;
    float run = 0.f;
    #pragma unroll
    for (int j = 0; j < 16; ++j) {
        size_t idx = ((size_t)bh * 16 + j) * 4096 + pos;
        split2(run, &ph[idx], &pl[idx]);
        run += Mst[idx];
    }
}

// ================= attention: out = Q@Pex + intra, /(cumg+eps), unit-norm =================
__global__ void attn_mfma(const u16* __restrict__ qh, const u16* __restrict__ ql,
                          const u16* __restrict__ pexh, const u16* __restrict__ pexl,
                          const u16* __restrict__ vcrh, const u16* __restrict__ vcrl,
                          const u16* __restrict__ kcth, const u16* __restrict__ kctl,
                          const float* __restrict__ g, const float* __restrict__ cumg,
                          u16* __restrict__ yh, u16* __restrict__ yl) {
    int tb = blockIdx.x, bh = blockIdx.y;
    int b = bh >> 3, h = bh & 7;
    int tid = threadIdx.x, w = tid >> 6, l = tid & 63;
    __shared__ __align__(16) u16 buf[6][64][72];
    __shared__ float gl_s[64], cg_s[64];
    #pragma unroll
    for (int p = 0; p < 2; ++p) {
        int i = tid + 256 * p; int r = i >> 3, c8 = (i & 7) * 8;
        size_t rowi = ((size_t)bh * 1024 + tb * 64 + r) * 64 + c8;
        size_t pexi = (((size_t)bh * 16 + tb) * 64 + r) * 64 + c8;
        *(bf16x8*)&buf[0][r][c8] = *(const bf16x8*)&qh[rowi];
        *(bf16x8*)&buf[1][r][c8] = *(const bf16x8*)&ql[rowi];
        *(bf16x8*)&buf[2][r][c8] = *(const bf16x8*)&pexh[pexi];
        *(bf16x8*)&buf[3][r][c8] = *(const bf16x8*)&pexl[pexi];
        *(bf16x8*)&buf[4][r][c8] = *(const bf16x8*)&vcrh[rowi];
        *(bf16x8*)&buf[5][r][c8] = *(const bf16x8*)&vcrl[rowi];
    }
    if (tid < 64) {
        gl_s[tid] = g[(size_t)bh * 1024 + tb * 64 + tid];
        cg_s[tid] = cumg[(size_t)bh * 1024 + tb * 64 + tid];
    }
    __syncthreads();
    f32x4 o[4] = {}, sc[4] = {};
    #pragma unroll
    for (int kc = 0; kc < 2; ++kc) {
        int ar = 16 * w + (l & 15), ac = kc * 32 + (l >> 4) * 8;
        bf16x8 ah = *(const bf16x8*)&buf[0][ar][ac];
        bf16x8 al = *(const bf16x8*)&buf[1][ar][ac];
        #pragma unroll
        for (int cf = 0; cf < 4; ++cf) {
            int br = cf * 16 + (l & 15);
            bf16x8 bph = *(const bf16x8*)&buf[2][br][ac];
            bf16x8 bpl = *(const bf16x8*)&buf[3][br][ac];
            bf16x8 bvh = *(const bf16x8*)&buf[4][br][ac];
            bf16x8 bvl = *(const bf16x8*)&buf[5][br][ac];
            o[cf] = MFMA16(ah, bph, o[cf]);
            o[cf] = MFMA16(ah, bpl, o[cf]);
            o[cf] = MFMA16(al, bph, o[cf]);
            sc[cf] = MFMA16(ah, bvh, sc[cf]);
            sc[cf] = MFMA16(ah, bvl, sc[cf]);
            sc[cf] = MFMA16(al, bvh, sc[cf]);
        }
    }
    __syncthreads();
    #pragma unroll
    for (int cf = 0; cf < 4; ++cf) {
        int s = cf * 16 + (l & 15);
        float gsv = gl_s[s];
        #pragma unroll
        for (int r = 0; r < 4; ++r) {
            int t = 16 * w + 4 * (l >> 4) + r;
            float v = (s <= t) ? sc[cf][r] * gsv : 0.f;
            split2(v, &buf[2][t][s], &buf[3][t][s]);
        }
    }
    #pragma unroll
    for (int p = 0; p < 2; ++p) {
        int i = tid + 256 * p; int r = i >> 3, c8 = (i & 7) * 8;
        size_t ti = ((size_t)bh * 64 + r) * 1024 + tb * 64 + c8;
        *(bf16x8*)&buf[4][r][c8] = *(const bf16x8*)&kcth[ti];
        *(bf16x8*)&buf[5][r][c8] = *(const bf16x8*)&kctl[ti];
    }
    __syncthreads();
    #pragma unroll
    for (int kc = 0; kc < 2; ++kc) {
        int ar = 16 * w + (l & 15), ac = kc * 32 + (l >> 4) * 8;
        bf16x8 ah = *(const bf16x8*)&buf[2][ar][ac];
        bf16x8 al = *(const bf16x8*)&buf[3][ar][ac];
        #pragma unroll
        for (int cf = 0; cf < 4; ++cf) {
            int br = cf * 16 + (l & 15);
            bf16x8 bh_ = *(const bf16x8*)&buf[4][br][ac];
            bf16x8 bl_ = *(const bf16x8*)&buf[5][br][ac];
            o[cf] = MFMA16(ah, bh_, o[cf]);
            o[cf] = MFMA16(ah, bl_, o[cf]);
            o[cf] = MFMA16(al, bh_, o[cf]);
        }
    }
    #pragma unroll
    for (int r = 0; r < 4; ++r) {
        int tl_ = 16 * w + 4 * (l >> 4) + r;
        float inv = 1.f / (cg_s[tl_] + EPS);
        float vv[4]; float sq = 0.f;
        #pragma unroll
        for (int cf = 0; cf < 4; ++cf) { vv[cf] = o[cf][r] * inv; sq += vv[cf] * vv[cf]; }
        #pragma unroll
        for (int off = 1; off < 16; off <<= 1) sq += __shfl_xor(sq, off);
        float scale = 1.f / fmaxf(sqrtf(sq), EPS);
        int tg = tb * 64 + tl_;
        #pragma unroll
        for (int cf = 0; cf < 4; ++cf) {
            int e = cf * 16 + (l & 15);
            size_t yi = ((size_t)b * 1024 + tg) * 512 + h * 64 + e;
            split2(vv[cf] * scale, &yh[yi], &yl[yi]);
        }
    }
}

extern "C" void kernel_launch(void* const* d_in, const int* in_sizes, int n_in,
                              void* d_out, int out_size, void* d_ws, size_t ws_size,
                              hipStream_t stream) {
    const float* x    = (const float*)d_in[0];
    const float* sbas = (const float*)d_in[1];
    const float* wq_w = (const float*)d_in[2];
    const float* wq_b = (const float*)d_in[3];
    const float* wk_w = (const float*)d_in[4];
    const float* wk_b = (const float*)d_in[5];
    const float* wv_w = (const float*)d_in[6];
    const float* wv_b = (const float*)d_in[7];
    const float* wo_w = (const float*)d_in[8];
    const float* wo_b = (const float*)d_in[9];
    const float* gw   = (const float*)d_in[10];
    const float* gb   = (const float*)d_in[11];
    float* out = (float*)d_out;

    char* p = (char*)d_ws;
    auto carve = [&](size_t bytes) { char* r = p; p += (bytes + 255) & ~(size_t)255; return r; };
    const size_t T2 = (size_t)2048 * 512 * 2;          // 2 MB (u16 plane)
    u16* xh = (u16*)carve(T2);      u16* xl = (u16*)carve(T2);
    u16* wqkvh = (u16*)carve((size_t)1536 * 512 * 2);
    u16* wqkvl = (u16*)carve((size_t)1536 * 512 * 2);
    u16* woh = (u16*)carve((size_t)512 * 512 * 2);
    u16* wol = (u16*)carve((size_t)512 * 512 * 2);
    u16* qh_ = (u16*)carve(T2);     u16* ql_ = (u16*)carve(T2);
    u16* kth_ = (u16*)carve(T2);    u16* ktl_ = (u16*)carve(T2);
    u16* vth_ = (u16*)carve(T2);    u16* vtl_ = (u16*)carve(T2);
    u16* Tth = (u16*)carve((size_t)8 * 16 * 4096 * 2);
    u16* Ttl = (u16*)carve((size_t)8 * 16 * 4096 * 2);
    float* Kacc = (float*)carve((size_t)16 * 1024 * 64 * 4);
    float* Vacc = (float*)carve((size_t)16 * 1024 * 64 * 4);
    u16* kcth_ = (u16*)carve(T2);   u16* kctl_ = (u16*)carve(T2);
    u16* vcrh_ = (u16*)carve(T2);   u16* vcrl_ = (u16*)carve(T2);
    u16* vcth_ = (u16*)carve(T2);   u16* vctl_ = (u16*)carve(T2);
    float* gbuf = (float*)carve((size_t)16 * 1024 * 4);
    float* cumg = (float*)carve((size_t)16 * 1024 * 4);
    float* Mst  = (float*)carve((size_t)16 * 16 * 4096 * 4);
    u16* pexh_ = (u16*)carve(T2);   u16* pexl_ = (u16*)carve(T2);
    u16* yh_ = (u16*)carve(T2);     u16* yl_ = (u16*)carve(T2);

    hipMemsetAsync(Kacc, 0, (size_t)16 * 1024 * 64 * 4 * 2, stream);
    prep_k<<<1408, 256, 0, stream>>>(x, wq_w, wk_w, wv_w, wo_w, sbas,
                                     xh, xl, wqkvh, wqkvl, woh, wol, Tth, Ttl);
    gemm3k<128, 1><<<dim3(32, 12), 512, 0, stream>>>(xh, xl, wqkvh, wqkvl, 1536,
                                                     wq_b, wk_b, wv_b, nullptr,
                                                     qh_, ql_, kth_, ktl_, vth_, vtl_);
    conv_part<<<dim3(40, 16), 256, 0, stream>>>(kth_, ktl_, vth_, vtl_, Tth, Ttl, Kacc, Vacc);
    conv_fin<<<dim3(16, 16), 256, 0, stream>>>(Kacc, Vacc, gw, gb,
                                               kcth_, kctl_, vcrh_, vcrl_, vcth_, vctl_, gbuf);
    scan_k<<<16, 256, 0, stream>>>(gbuf, cumg);
    states_mfma<<<dim3(16, 16), 256, 0, stream>>>(kcth_, kctl_, vcth_, vctl_, gbuf, Mst);
    state_prefix<<<dim3(16, 16), 256, 0, stream>>>(Mst, pexh_, pexl_);
    attn_mfma<<<dim3(16, 16), 256, 0, stream>>>(qh_, ql_, pexh_, pexl_, vcrh_, vcrl_,
                                                kcth_, kctl_, gbuf, cumg, yh_, yl_);
    gemm3k<64, 0><<<dim3(32, 8), 256, 0, stream>>>(yh_, yl_, woh, wol, 512,
                                                   wo_b, nullptr, nullptr, out,
                                                   nullptr, nullptr, nullptr, nullptr, nullptr, nullptr);
}